// Round 1
// baseline (43.107 us; speedup 1.0000x reference)
//
#include <hip/hip_runtime.h>

// AdaIN stats: per-(b,c) mean and unbiased std over 64x64 spatial dims.
// Input: f_vol [32, 512, 64, 64] fp32 (contiguous). Output: [32, 1024] fp32,
// out[b][c] = mean(b,c) for c<512, out[b][512+c] = std(b,c, ddof=1).

#define NSPATIAL 4096   // 64*64
#define NCH      512

__global__ __launch_bounds__(256) void adain_stats_kernel(
    const float* __restrict__ in, float* __restrict__ out) {
    const int bc = blockIdx.x;          // 0 .. 32*512-1, one block per row
    const int b  = bc >> 9;             // / 512
    const int c  = bc & (NCH - 1);      // % 512

    const float4* __restrict__ p =
        reinterpret_cast<const float4*>(in + (size_t)bc * NSPATIAL);
    const int t = threadIdx.x;

    float s = 0.0f, q = 0.0f;
#pragma unroll
    for (int i = 0; i < 4; ++i) {
        // iteration i covers elements [i*1024, (i+1)*1024): fully coalesced,
        // 16B per lane.
        float4 v = p[i * 256 + t];
        s += v.x + v.y + v.z + v.w;
        q += v.x * v.x + v.y * v.y + v.z * v.z + v.w * v.w;
    }

    // 64-lane wave reduction (wavefront = 64 on CDNA)
#pragma unroll
    for (int off = 32; off > 0; off >>= 1) {
        s += __shfl_down(s, off);
        q += __shfl_down(q, off);
    }

    __shared__ float s_sum[4];
    __shared__ float s_sq[4];
    const int wave = t >> 6;
    if ((t & 63) == 0) { s_sum[wave] = s; s_sq[wave] = q; }
    __syncthreads();

    if (t == 0) {
        float S = s_sum[0] + s_sum[1] + s_sum[2] + s_sum[3];
        float Q = s_sq[0] + s_sq[1] + s_sq[2] + s_sq[3];
        float mean = S * (1.0f / NSPATIAL);
        float var  = (Q - S * mean) * (1.0f / (NSPATIAL - 1));
        var = fmaxf(var, 0.0f);
        out[b * (2 * NCH) + c]       = mean;
        out[b * (2 * NCH) + NCH + c] = sqrtf(var);
    }
}

extern "C" void kernel_launch(void* const* d_in, const int* in_sizes, int n_in,
                              void* d_out, int out_size, void* d_ws, size_t ws_size,
                              hipStream_t stream) {
    const float* in = (const float*)d_in[0];
    float* out = (float*)d_out;
    const int nrows = 32 * NCH;  // 16384 blocks
    adain_stats_kernel<<<nrows, 256, 0, stream>>>(in, out);
}